// Round 11
// baseline (106.775 us; speedup 1.0000x reference)
//
#include <hip/hip_runtime.h>
#include <hip/hip_bf16.h>

#define B_    2
#define CIN   4
#define COUT  8
#define KK    4
#define DD    2
#define NN    224
#define FDIM  128
#define NH    218
#define NSUB  (NH*NH)         // 47524
#define NPERM 24
#define NROWS (B_*COUT*CIN)   // 64 softmax rows
#define NSUB4 (NSUB/4)        // 11881 float4s per row
#define CH4   512             // float4s per chunk
#define MB    ((NSUB4 + CH4 - 1) / CH4)   // 24 chunk-blocks per row
#define NEGBIG (-3.4e38f)
#define NCOL  192             // p-major columns: col = p*8 + o
#define MTILE 128             // rows per block
#define NBLK  ((NSUB + MTILE - 1) / MTILE)  // 372
#define STR   40              // LDS row stride (ushorts): 80B = 2-way-free banks

typedef short short8 __attribute__((ext_vector_type(8)));
typedef float f32x4 __attribute__((ext_vector_type(4)));
typedef unsigned short ushort_t;

__device__ static constexpr int PERM[NPERM][4] = {
  {0,1,2,3},{0,1,3,2},{0,2,1,3},{0,2,3,1},{0,3,1,2},{0,3,2,1},
  {1,0,2,3},{1,0,3,2},{1,2,0,3},{1,2,3,0},{1,3,0,2},{1,3,2,0},
  {2,0,1,3},{2,0,3,1},{2,1,0,3},{2,1,3,0},{2,3,0,1},{2,3,1,0},
  {3,0,1,2},{3,0,2,1},{3,1,0,2},{3,1,2,0},{3,2,0,1},{3,2,1,0}
};

__device__ __forceinline__ void bf16split(float v, ushort_t* h, ushort_t* l) {
  __hip_bfloat16 hh = __float2bfloat16(v);
  float hf = __bfloat162float(hh);
  __hip_bfloat16 ll = __float2bfloat16(v - hf);
  *h = *(const ushort_t*)&hh;
  *l = *(const ushort_t*)&ll;
}

// build permuted weight table BTg[ci][col][32] (bf16 hi/lo) + K2g[ci*8+o]
__global__ __launch_bounds__(256) void prep_kernel(
    const float* __restrict__ ks, const float* __restrict__ kr,
    const float* __restrict__ kc, ushort_t* __restrict__ BTgHi,
    ushort_t* __restrict__ BTgLo, float* __restrict__ K2g)
{
  int t = threadIdx.x;
  for (int idx = t; idx < CIN * NCOL; idx += 256) {
    int ci = idx / NCOL, col = idx - ci * NCOL;
    int p = col >> 3, o = col & 7;
    int oc = o * CIN + ci;
    const int* pr = PERM[p];
    float vals[32];
#pragma unroll
    for (int a = 0; a < 4; ++a) {
#pragma unroll
      for (int bb = 0; bb < 4; ++bb)
        vals[a * 4 + bb] = ks[oc * 16 + pr[a] * 4 + pr[bb]];
      vals[16 + a] = kr[oc * 4 + pr[a]];
      vals[20 + a] = kc[oc * 4 + pr[a]];
    }
#pragma unroll
    for (int u = 24; u < 32; ++u) vals[u] = 0.f;
    ushort_t* dh = BTgHi + idx * 32;
    ushort_t* dl = BTgLo + idx * 32;
#pragma unroll
    for (int u = 0; u < 32; ++u) bf16split(vals[u], dh + u, dl + u);
  }
  if (t < 32) {
    int ci = t >> 3, o = t & 7, oc = o * CIN + ci;
    float s2 = 0.f;
#pragma unroll
    for (int u = 0; u < 16; ++u) s2 += ks[oc * 16 + u] * ks[oc * 16 + u];
#pragma unroll
    for (int u = 0; u < 4; ++u)
      s2 += kr[oc * 4 + u] * kr[oc * 4 + u] + kc[oc * 4 + u] * kc[oc * 4 + u];
    K2g[t] = s2;   // [ci*8 + o]
  }
}

// one wave per (b,f): lanes split r, shuffle-reduce
__global__ __launch_bounds__(64) void hmean_kernel(const float* __restrict__ features,
                                                   float* __restrict__ out) {
  int bf = blockIdx.x;
  int b = bf / FDIM, f = bf - b * FDIM;
  int lane = threadIdx.x;
  const float* fb = features + (size_t)b * NN * FDIM + f;
  float acc = 0.f;
  for (int r = lane; r < NN; r += 64) {
    int w = 0;
#pragma unroll
    for (int a = 0; a < KK; ++a) {
      int i0 = r - a * DD;
      if (0 <= i0 && i0 < NH) w++;
    }
    acc += (float)w * fb[(size_t)r * FDIM];
  }
#pragma unroll
  for (int off = 32; off > 0; off >>= 1) acc += __shfl_down(acc, off, 64);
  if (lane == 0) out[bf] = acc * (2.0f / (float)NH);
}

// grid (NBLK, B_): block = 128 n-rows for one b; loop ci: stage x (hi/lo bf16)
// + copy BT tile -> MFMA GEMM (split-bf16, 3 terms) -> p-max in regs -> sims.
__global__ __launch_bounds__(256, 2) void sims_mfma_kernel(
    const float* __restrict__ graph, const float* __restrict__ types,
    const ushort_t* __restrict__ BTgHi, const ushort_t* __restrict__ BTgLo,
    const float* __restrict__ K2g, float* __restrict__ simsOut)
{
  __shared__ ushort_t lsAhi[MTILE * STR];
  __shared__ ushort_t lsAlo[MTILE * STR];
  __shared__ ushort_t lsBThi[NCOL * STR];
  __shared__ ushort_t lsBTlo[NCOL * STR];
  __shared__ float lsBase[MTILE];
  __shared__ float lsK2[8];

  int t = threadIdx.x;
  int s_base = blockIdx.x * MTILE;
  int b = blockIdx.y;
  int wv = t >> 6, lane = t & 63;
  int c16 = lane & 15, quad = lane >> 4;

#pragma unroll 1
  for (int ci = 0; ci < CIN; ++ci) {
    __syncthreads();   // previous ci's reads complete before overwrite
    if (t < 128) {
      // stage one x-row: 16 graph + 4 row-type + 4 col-type, fp32 sq-sum
      int r = t;
      int s = s_base + r;
      float xv[24];
      if (s < NSUB) {
        int ii = s / NH, jj = s - ii * NH;
        const float* gi = graph + (size_t)(b * CIN + ci) * NN * NN;
        const float* ti = types + (size_t)(b * CIN + ci) * NN;
        float bsum = 0.f;
#pragma unroll
        for (int a = 0; a < 4; ++a) {
          const float* row = gi + (size_t)(ii + a * DD) * NN + jj;
#pragma unroll
          for (int bb = 0; bb < 4; ++bb) {
            float v = row[bb * DD];
            xv[a * 4 + bb] = v;
            bsum += v * v;
          }
          float rv = ti[ii + a * DD];
          float cv = ti[jj + a * DD];
          xv[16 + a] = rv; xv[20 + a] = cv;
          bsum += rv * rv + cv * cv;
        }
        lsBase[r] = bsum;
      } else {
#pragma unroll
        for (int u = 0; u < 24; ++u) xv[u] = 0.f;
        lsBase[r] = 0.f;
      }
      ushort_t* ah = lsAhi + r * STR;
      ushort_t* al = lsAlo + r * STR;
#pragma unroll
      for (int u = 0; u < 24; ++u) bf16split(xv[u], ah + u, al + u);
#pragma unroll
      for (int u = 24; u < 32; ++u) { ah[u] = 0; al[u] = 0; }
      if (t < 8) lsK2[t] = K2g[ci * 8 + t];
    } else {
      // copy this ci's BT tile (packed [192][32]) into strided LDS
      int tt = t - 128;
      const ushort_t* srcH = BTgHi + ci * (NCOL * 32);
      const ushort_t* srcL = BTgLo + ci * (NCOL * 32);
#pragma unroll
      for (int i = tt; i < NCOL * 4; i += 128) {   // 768 chunks of 8 ushorts
        int col = i >> 2, part = i & 3;
        *(short8*)(lsBThi + col * STR + part * 8) = *(const short8*)(srcH + i * 8);
        *(short8*)(lsBTlo + col * STR + part * 8) = *(const short8*)(srcL + i * 8);
      }
    }
    __syncthreads();

    // GEMM: wave handles M-tiles {wv*2, wv*2+1}; N in 2 halves of 6 frags
    float mx[2][4];
#pragma unroll
    for (int m2 = 0; m2 < 2; ++m2)
#pragma unroll
      for (int rr = 0; rr < 4; ++rr) mx[m2][rr] = NEGBIG;

#pragma unroll 1
    for (int half = 0; half < 2; ++half) {
      short8 bh[6], bl[6];
#pragma unroll
      for (int j = 0; j < 6; ++j) {
        int col = (half * 6 + j) * 16 + c16;
        bh[j] = *(const short8*)(lsBThi + col * STR + quad * 8);
        bl[j] = *(const short8*)(lsBTlo + col * STR + quad * 8);
      }
#pragma unroll
      for (int m2 = 0; m2 < 2; ++m2) {
        int mt = wv * 2 + m2;
        int arow = mt * 16 + c16;
        short8 ah = *(const short8*)(lsAhi + arow * STR + quad * 8);
        short8 al = *(const short8*)(lsAlo + arow * STR + quad * 8);
#pragma unroll
        for (int j = 0; j < 6; ++j) {
          f32x4 c = {0.f, 0.f, 0.f, 0.f};
          c = __builtin_amdgcn_mfma_f32_16x16x32_bf16(ah, bh[j], c, 0, 0, 0);
          c = __builtin_amdgcn_mfma_f32_16x16x32_bf16(ah, bl[j], c, 0, 0, 0);
          c = __builtin_amdgcn_mfma_f32_16x16x32_bf16(al, bh[j], c, 0, 0, 0);
#pragma unroll
          for (int rr = 0; rr < 4; ++rr) mx[m2][rr] = fmaxf(mx[m2][rr], c[rr]);
        }
      }
    }

    // p-max across parity (lane^8), then sims = base0 + K2 - 2*max
    int o = lane & 7;
    float k2o = lsK2[o];
    bool writer = (lane & 8) == 0;
#pragma unroll
    for (int m2 = 0; m2 < 2; ++m2) {
      int mt = wv * 2 + m2;
#pragma unroll
      for (int rr = 0; rr < 4; ++rr) {
        float v = mx[m2][rr];
        v = fmaxf(v, __shfl_xor(v, 8, 64));
        int m = mt * 16 + quad * 4 + rr;
        int s = s_base + m;
        if (writer && s < NSUB) {
          float val = lsBase[m] + k2o - 2.0f * v;
          simsOut[(size_t)((b * COUT + o) * CIN + ci) * NSUB + s] = val;
        }
      }
    }
  }
}

// grid (MB, NROWS): per-chunk (m, sumexp) partials, float4 streaming.
__global__ __launch_bounds__(256) void softmax_partial(const float* __restrict__ sims,
                                                       float* __restrict__ partial) {
  int ch = blockIdx.x, row = blockIdx.y;
  int base4 = ch * CH4;
  int n4 = NSUB4 - base4; if (n4 > CH4) n4 = CH4;
  const float4* rp = (const float4*)(sims + (size_t)row * NSUB) + base4;
  int t = threadIdx.x;
  int wave = t >> 6, lane = t & 63;

  float4 a0, a1;
  bool h0 = (t < n4), h1 = (t + 256 < n4);
  if (h0) a0 = rp[t];
  if (h1) a1 = rp[t + 256];

  float m = NEGBIG;
  if (h0) m = fmaxf(fmaxf(a0.x, a0.y), fmaxf(a0.z, a0.w));
  if (h1) m = fmaxf(m, fmaxf(fmaxf(a1.x, a1.y), fmaxf(a1.z, a1.w)));
#pragma unroll
  for (int off = 32; off > 0; off >>= 1) m = fmaxf(m, __shfl_down(m, off, 64));
  __shared__ float red[8];
  if (lane == 0) red[wave] = m;
  __syncthreads();
  float M = fmaxf(fmaxf(red[0], red[1]), fmaxf(red[2], red[3]));

  float e = 0.f;
  if (h0) e  = __expf(a0.x - M) + __expf(a0.y - M) + __expf(a0.z - M) + __expf(a0.w - M);
  if (h1) e += __expf(a1.x - M) + __expf(a1.y - M) + __expf(a1.z - M) + __expf(a1.w - M);
#pragma unroll
  for (int off = 32; off > 0; off >>= 1) e += __shfl_down(e, off, 64);
  if (lane == 0) red[4 + wave] = e;
  __syncthreads();
  if (t == 0) {
    int idx = (row * MB + ch) * 2;
    partial[idx] = M;
    partial[idx + 1] = red[4] + red[5] + red[6] + red[7];
  }
}

// grid (MB, NROWS): fused combine (MB partials per row) + in-place transform.
__global__ __launch_bounds__(256) void softmax_final(float* __restrict__ sims,
                                                     const float* __restrict__ partial) {
  int ch = blockIdx.x, row = blockIdx.y;
  int t = threadIdx.x;

  __shared__ float sM, sInv;
  if (t < 64) {
    const float* pp = partial + row * MB * 2;
    float m = NEGBIG, l = 0.f;
    if (t < MB) { m = pp[2 * t]; l = pp[2 * t + 1]; }
#pragma unroll
    for (int off = 32; off > 0; off >>= 1) {
      float m2 = __shfl_down(m, off, 64);
      float l2 = __shfl_down(l, off, 64);
      float M = fmaxf(m, m2);
      l = l * __expf(m - M) + l2 * __expf(m2 - M);
      m = M;
    }
    if (t == 0) { sM = m; sInv = 1.0f / l; }
  }
  __syncthreads();
  float M = sM, invS = sInv;

  int base4 = ch * CH4;
  int n4 = NSUB4 - base4; if (n4 > CH4) n4 = CH4;
  float4* rp = (float4*)(sims + (size_t)row * NSUB) + base4;
  const float scale = 1.0f / (float)NSUB;
  for (int i = t; i < n4; i += 256) {
    float4 v = rp[i];
    v.x = (1.0f - __expf(v.x - M) * invS) * scale;
    v.y = (1.0f - __expf(v.y - M) * invS) * scale;
    v.z = (1.0f - __expf(v.z - M) * invS) * scale;
    v.w = (1.0f - __expf(v.w - M) * invS) * scale;
    rp[i] = v;
  }
}

extern "C" void kernel_launch(void* const* d_in, const int* in_sizes, int n_in,
                              void* d_out, int out_size, void* d_ws, size_t ws_size,
                              hipStream_t stream) {
  const float* graph    = (const float*)d_in[0];
  const float* types    = (const float*)d_in[1];
  const float* features = (const float*)d_in[2];
  const float* ks       = (const float*)d_in[3];
  const float* kr       = (const float*)d_in[4];
  const float* kc       = (const float*)d_in[5];
  float* out  = (float*)d_out;
  float* sims = out + B_ * FDIM;

  // d_ws layout: [0,12288) partial | 16384: BTgHi 49152 | 65536+16384: BTgLo | K2g
  float* partial  = (float*)d_ws;
  ushort_t* BTgHi = (ushort_t*)((char*)d_ws + 16384);
  ushort_t* BTgLo = (ushort_t*)((char*)d_ws + 16384 + 49152);
  float* K2g      = (float*)((char*)d_ws + 16384 + 2 * 49152);

  prep_kernel<<<1, 256, 0, stream>>>(ks, kr, kc, BTgHi, BTgLo, K2g);
  hmean_kernel<<<B_ * FDIM, 64, 0, stream>>>(features, out);
  dim3 ggrid(NBLK, B_);
  sims_mfma_kernel<<<ggrid, 256, 0, stream>>>(graph, types, BTgHi, BTgLo, K2g, sims);
  dim3 pgrid(MB, NROWS);
  softmax_partial<<<pgrid, 256, 0, stream>>>(sims, partial);
  softmax_final<<<pgrid, 256, 0, stream>>>(sims, partial);
}

// Round 12
// 105.422 us; speedup vs baseline: 1.0128x; 1.0128x over previous
//
#include <hip/hip_runtime.h>
#include <hip/hip_bf16.h>

#define B_    2
#define CIN   4
#define COUT  8
#define KK    4
#define DD    2
#define NN    224
#define FDIM  128
#define NH    218
#define NSUB  (NH*NH)         // 47524
#define NPERM 24
#define NROWS (B_*COUT*CIN)   // 64 softmax rows
#define NSUB4 (NSUB/4)        // 11881 float4s per row
#define CH4   512             // float4s per chunk
#define MB    ((NSUB4 + CH4 - 1) / CH4)   // 24 chunk-blocks per row
#define NEGBIG (-3.4e38f)
#define NCOL  192             // p-major columns: col = p*8 + o
#define MTILE 128             // s-rows per block
#define NBLK  ((NSUB + MTILE - 1) / MTILE)  // 372
#define STR   40              // LDS row stride (ushorts): 80B

typedef short short8 __attribute__((ext_vector_type(8)));
typedef float f32x4 __attribute__((ext_vector_type(4)));
typedef unsigned short ushort_t;

__device__ static constexpr int PERM[NPERM][4] = {
  {0,1,2,3},{0,1,3,2},{0,2,1,3},{0,2,3,1},{0,3,1,2},{0,3,2,1},
  {1,0,2,3},{1,0,3,2},{1,2,0,3},{1,2,3,0},{1,3,0,2},{1,3,2,0},
  {2,0,1,3},{2,0,3,1},{2,1,0,3},{2,1,3,0},{2,3,0,1},{2,3,1,0},
  {3,0,1,2},{3,0,2,1},{3,1,0,2},{3,1,2,0},{3,2,0,1},{3,2,1,0}
};

__device__ __forceinline__ void bf16split(float v, ushort_t* h, ushort_t* l) {
  __hip_bfloat16 hh = __float2bfloat16(v);
  float hf = __bfloat162float(hh);
  __hip_bfloat16 ll = __float2bfloat16(v - hf);
  *h = *(const ushort_t*)&hh;
  *l = *(const ushort_t*)&ll;
}

// grid 4 blocks: gid<768 build permuted table; gid in [768,800) K2.
__global__ __launch_bounds__(256) void prep_kernel(
    const float* __restrict__ ks, const float* __restrict__ kr,
    const float* __restrict__ kc, ushort_t* __restrict__ BTgHi,
    ushort_t* __restrict__ BTgLo, float* __restrict__ K2g)
{
  int gid = blockIdx.x * 256 + threadIdx.x;
  if (gid < CIN * NCOL) {
    int ci = gid / NCOL, col = gid - ci * NCOL;
    int p = col >> 3, o = col & 7;
    int oc = o * CIN + ci;
    const int* pr = PERM[p];
    float vals[32];
#pragma unroll
    for (int a = 0; a < 4; ++a) {
#pragma unroll
      for (int bb = 0; bb < 4; ++bb)
        vals[a * 4 + bb] = ks[oc * 16 + pr[a] * 4 + pr[bb]];
      vals[16 + a] = kr[oc * 4 + pr[a]];
      vals[20 + a] = kc[oc * 4 + pr[a]];
    }
#pragma unroll
    for (int u = 24; u < 32; ++u) vals[u] = 0.f;
    ushort_t* dh = BTgHi + gid * 32;
    ushort_t* dl = BTgLo + gid * 32;
#pragma unroll
    for (int u = 0; u < 32; ++u) bf16split(vals[u], dh + u, dl + u);
  } else if (gid < CIN * NCOL + 32) {
    int t = gid - CIN * NCOL;
    int ci = t >> 3, o = t & 7, oc = o * CIN + ci;
    float s2 = 0.f;
#pragma unroll
    for (int u = 0; u < 16; ++u) s2 += ks[oc * 16 + u] * ks[oc * 16 + u];
#pragma unroll
    for (int u = 0; u < 4; ++u)
      s2 += kr[oc * 4 + u] * kr[oc * 4 + u] + kc[oc * 4 + u] * kc[oc * 4 + u];
    K2g[t] = s2;   // [ci*8 + o]
  }
}

// one wave per (b,f): lanes split r, shuffle-reduce
__global__ __launch_bounds__(64) void hmean_kernel(const float* __restrict__ features,
                                                   float* __restrict__ out) {
  int bf = blockIdx.x;
  int b = bf / FDIM, f = bf - b * FDIM;
  int lane = threadIdx.x;
  const float* fb = features + (size_t)b * NN * FDIM + f;
  float acc = 0.f;
  for (int r = lane; r < NN; r += 64) {
    int w = 0;
#pragma unroll
    for (int a = 0; a < KK; ++a) {
      int i0 = r - a * DD;
      if (0 <= i0 && i0 < NH) w++;
    }
    acc += (float)w * fb[(size_t)r * FDIM];
  }
#pragma unroll
  for (int off = 32; off > 0; off >>= 1) acc += __shfl_down(acc, off, 64);
  if (lane == 0) out[bf] = acc * (2.0f / (float)NH);
}

// grid (NBLK, B_*CIN): one (b,ci) per block, 128 s-rows. Single staging phase,
// single barrier, one GEMM (split-bf16, 3 MFMA terms), p-fold, write.
__global__ __launch_bounds__(256, 3) void sims_mfma_kernel(
    const float* __restrict__ graph, const float* __restrict__ types,
    const ushort_t* __restrict__ BTgHi, const ushort_t* __restrict__ BTgLo,
    const float* __restrict__ K2g, float* __restrict__ simsOut)
{
  __shared__ ushort_t lsAhi[MTILE * STR];
  __shared__ ushort_t lsAlo[MTILE * STR];
  __shared__ ushort_t lsBThi[NCOL * STR];
  __shared__ ushort_t lsBTlo[NCOL * STR];
  __shared__ float lsBase[MTILE];
  __shared__ float lsK2[8];

  int t = threadIdx.x;
  int s_base = blockIdx.x * MTILE;
  int bci = blockIdx.y;
  int b = bci >> 2, ci = bci & 3;
  int wv = t >> 6, lane = t & 63;
  int c16 = lane & 15, quad = lane >> 4;

  // B-tile copy: all 256 threads, 1536 16B-chunks (hi then lo)
  {
    const ushort_t* srcH = BTgHi + ci * (NCOL * 32);
    const ushort_t* srcL = BTgLo + ci * (NCOL * 32);
#pragma unroll
    for (int i = t; i < 2 * NCOL * 4; i += 256) {
      int isLo = i >= NCOL * 4;
      int j = isLo ? i - NCOL * 4 : i;
      int col = j >> 2, part = j & 3;
      const ushort_t* src = (isLo ? srcL : srcH) + j * 8;
      ushort_t* dst = (isLo ? lsBTlo : lsBThi) + col * STR + part * 8;
      *(short8*)dst = *(const short8*)src;
    }
  }
  if (t < 8) lsK2[t] = K2g[ci * 8 + t];

  // A staging: threads 0..127, one s-row each
  if (t < 128) {
    int r = t;
    int s = s_base + r;
    float xv[24];
    if (s < NSUB) {
      int ii = s / NH, jj = s - ii * NH;
      const float* gi = graph + (size_t)(b * CIN + ci) * NN * NN;
      const float* ti = types + (size_t)(b * CIN + ci) * NN;
      float bsum = 0.f;
#pragma unroll
      for (int a = 0; a < 4; ++a) {
        const float* row = gi + (size_t)(ii + a * DD) * NN + jj;
#pragma unroll
        for (int bb = 0; bb < 4; ++bb) {
          float v = row[bb * DD];
          xv[a * 4 + bb] = v;
          bsum += v * v;
        }
        float rv = ti[ii + a * DD];
        float cv = ti[jj + a * DD];
        xv[16 + a] = rv; xv[20 + a] = cv;
        bsum += rv * rv + cv * cv;
      }
      lsBase[r] = bsum;
    } else {
#pragma unroll
      for (int u = 0; u < 24; ++u) xv[u] = 0.f;
      lsBase[r] = 0.f;
    }
    ushort_t* ah = lsAhi + r * STR;
    ushort_t* al = lsAlo + r * STR;
#pragma unroll
    for (int u = 0; u < 24; ++u) bf16split(xv[u], ah + u, al + u);
#pragma unroll
    for (int u = 24; u < 32; ++u) { ah[u] = 0; al[u] = 0; }
  }
  __syncthreads();

  // GEMM: each wave does m-tiles {2wv, 2wv+1} x all 12 n-tiles
  short8 ah2[2], al2[2];
#pragma unroll
  for (int m2 = 0; m2 < 2; ++m2) {
    int arow = (wv * 2 + m2) * 16 + c16;
    ah2[m2] = *(const short8*)(lsAhi + arow * STR + quad * 8);
    al2[m2] = *(const short8*)(lsAlo + arow * STR + quad * 8);
  }

  float mx[2][4];
#pragma unroll
  for (int m2 = 0; m2 < 2; ++m2)
#pragma unroll
    for (int rr = 0; rr < 4; ++rr) mx[m2][rr] = NEGBIG;

#pragma unroll 1
  for (int half = 0; half < 2; ++half) {
    short8 bh[6], bl[6];
#pragma unroll
    for (int j = 0; j < 6; ++j) {
      int col = (half * 6 + j) * 16 + c16;
      bh[j] = *(const short8*)(lsBThi + col * STR + quad * 8);
      bl[j] = *(const short8*)(lsBTlo + col * STR + quad * 8);
    }
#pragma unroll
    for (int m2 = 0; m2 < 2; ++m2) {
#pragma unroll
      for (int j = 0; j < 6; ++j) {
        f32x4 c = {0.f, 0.f, 0.f, 0.f};
        c = __builtin_amdgcn_mfma_f32_16x16x32_bf16(ah2[m2], bh[j], c, 0, 0, 0);
        c = __builtin_amdgcn_mfma_f32_16x16x32_bf16(ah2[m2], bl[j], c, 0, 0, 0);
        c = __builtin_amdgcn_mfma_f32_16x16x32_bf16(al2[m2], bh[j], c, 0, 0, 0);
#pragma unroll
        for (int rr = 0; rr < 4; ++rr) mx[m2][rr] = fmaxf(mx[m2][rr], c[rr]);
      }
    }
  }

  // p-fold across lane^8 (same o, other p-parity), then write
  int o = lane & 7;
  float k2o = lsK2[o];
  bool writer = (lane & 8) == 0;
#pragma unroll
  for (int m2 = 0; m2 < 2; ++m2) {
    int mt = wv * 2 + m2;
#pragma unroll
    for (int rr = 0; rr < 4; ++rr) {
      float v = mx[m2][rr];
      v = fmaxf(v, __shfl_xor(v, 8, 64));
      int m = mt * 16 + quad * 4 + rr;
      int s = s_base + m;
      if (writer && s < NSUB) {
        float val = lsBase[m] + k2o - 2.0f * v;
        simsOut[(size_t)((b * COUT + o) * CIN + ci) * NSUB + s] = val;
      }
    }
  }
}

// grid (MB, NROWS): per-chunk (m, sumexp) partials, float4 streaming.
__global__ __launch_bounds__(256) void softmax_partial(const float* __restrict__ sims,
                                                       float* __restrict__ partial) {
  int ch = blockIdx.x, row = blockIdx.y;
  int base4 = ch * CH4;
  int n4 = NSUB4 - base4; if (n4 > CH4) n4 = CH4;
  const float4* rp = (const float4*)(sims + (size_t)row * NSUB) + base4;
  int t = threadIdx.x;
  int wave = t >> 6, lane = t & 63;

  float4 a0, a1;
  bool h0 = (t < n4), h1 = (t + 256 < n4);
  if (h0) a0 = rp[t];
  if (h1) a1 = rp[t + 256];

  float m = NEGBIG;
  if (h0) m = fmaxf(fmaxf(a0.x, a0.y), fmaxf(a0.z, a0.w));
  if (h1) m = fmaxf(m, fmaxf(fmaxf(a1.x, a1.y), fmaxf(a1.z, a1.w)));
#pragma unroll
  for (int off = 32; off > 0; off >>= 1) m = fmaxf(m, __shfl_down(m, off, 64));
  __shared__ float red[8];
  if (lane == 0) red[wave] = m;
  __syncthreads();
  float M = fmaxf(fmaxf(red[0], red[1]), fmaxf(red[2], red[3]));

  float e = 0.f;
  if (h0) e  = __expf(a0.x - M) + __expf(a0.y - M) + __expf(a0.z - M) + __expf(a0.w - M);
  if (h1) e += __expf(a1.x - M) + __expf(a1.y - M) + __expf(a1.z - M) + __expf(a1.w - M);
#pragma unroll
  for (int off = 32; off > 0; off >>= 1) e += __shfl_down(e, off, 64);
  if (lane == 0) red[4 + wave] = e;
  __syncthreads();
  if (t == 0) {
    int idx = (row * MB + ch) * 2;
    partial[idx] = M;
    partial[idx + 1] = red[4] + red[5] + red[6] + red[7];
  }
}

// grid (MB, NROWS): fused combine (MB partials per row) + in-place transform.
__global__ __launch_bounds__(256) void softmax_final(float* __restrict__ sims,
                                                     const float* __restrict__ partial) {
  int ch = blockIdx.x, row = blockIdx.y;
  int t = threadIdx.x;

  __shared__ float sM, sInv;
  if (t < 64) {
    const float* pp = partial + row * MB * 2;
    float m = NEGBIG, l = 0.f;
    if (t < MB) { m = pp[2 * t]; l = pp[2 * t + 1]; }
#pragma unroll
    for (int off = 32; off > 0; off >>= 1) {
      float m2 = __shfl_down(m, off, 64);
      float l2 = __shfl_down(l, off, 64);
      float M = fmaxf(m, m2);
      l = l * __expf(m - M) + l2 * __expf(m2 - M);
      m = M;
    }
    if (t == 0) { sM = m; sInv = 1.0f / l; }
  }
  __syncthreads();
  float M = sM, invS = sInv;

  int base4 = ch * CH4;
  int n4 = NSUB4 - base4; if (n4 > CH4) n4 = CH4;
  float4* rp = (float4*)(sims + (size_t)row * NSUB) + base4;
  const float scale = 1.0f / (float)NSUB;
  for (int i = t; i < n4; i += 256) {
    float4 v = rp[i];
    v.x = (1.0f - __expf(v.x - M) * invS) * scale;
    v.y = (1.0f - __expf(v.y - M) * invS) * scale;
    v.z = (1.0f - __expf(v.z - M) * invS) * scale;
    v.w = (1.0f - __expf(v.w - M) * invS) * scale;
    rp[i] = v;
  }
}

extern "C" void kernel_launch(void* const* d_in, const int* in_sizes, int n_in,
                              void* d_out, int out_size, void* d_ws, size_t ws_size,
                              hipStream_t stream) {
  const float* graph    = (const float*)d_in[0];
  const float* types    = (const float*)d_in[1];
  const float* features = (const float*)d_in[2];
  const float* ks       = (const float*)d_in[3];
  const float* kr       = (const float*)d_in[4];
  const float* kc       = (const float*)d_in[5];
  float* out  = (float*)d_out;
  float* sims = out + B_ * FDIM;

  float* partial  = (float*)d_ws;
  ushort_t* BTgHi = (ushort_t*)((char*)d_ws + 16384);
  ushort_t* BTgLo = (ushort_t*)((char*)d_ws + 16384 + 49152);
  float* K2g      = (float*)((char*)d_ws + 16384 + 2 * 49152);

  prep_kernel<<<4, 256, 0, stream>>>(ks, kr, kc, BTgHi, BTgLo, K2g);
  hmean_kernel<<<B_ * FDIM, 64, 0, stream>>>(features, out);
  dim3 ggrid(NBLK, B_ * CIN);
  sims_mfma_kernel<<<ggrid, 256, 0, stream>>>(graph, types, BTgHi, BTgLo, K2g, sims);
  dim3 pgrid(MB, NROWS);
  softmax_partial<<<pgrid, 256, 0, stream>>>(sims, partial);
  softmax_final<<<pgrid, 256, 0, stream>>>(sims, partial);
}

// Round 13
// 102.002 us; speedup vs baseline: 1.0468x; 1.0335x over previous
//
#include <hip/hip_runtime.h>
#include <hip/hip_bf16.h>

#define B_    2
#define CIN   4
#define COUT  8
#define KK    4
#define DD    2
#define NN    224
#define FDIM  128
#define NH    218
#define NSUB  (NH*NH)         // 47524
#define NPERM 24
#define NROWS (B_*COUT*CIN)   // 64 softmax rows
#define NSUB4 (NSUB/4)        // 11881 float4s per row
#define CH4   512             // float4s per chunk
#define MB    ((NSUB4 + CH4 - 1) / CH4)   // 24 chunk-blocks per row
#define OG    2               // o-split; each thread handles COUT/OG = 4 o's
#define NCH2  ((NSUB + 511) / 512)        // 93 s-chunks (512 s per block, 2/thread)
#define NW    4               // waves per block
#define NPART (NCH2*NW)       // 372 (m,l) partials per softmax row
#define NEGBIG (-3.4e38f)

typedef float v2f __attribute__((ext_vector_type(2)));

__device__ static constexpr int PERM[NPERM][4] = {
  {0,1,2,3},{0,1,3,2},{0,2,1,3},{0,2,3,1},{0,3,1,2},{0,3,2,1},
  {1,0,2,3},{1,0,3,2},{1,2,0,3},{1,2,3,0},{1,3,0,2},{1,3,2,0},
  {2,0,1,3},{2,0,3,1},{2,1,0,3},{2,1,3,0},{2,3,0,1},{2,3,1,0},
  {3,0,1,2},{3,0,2,1},{3,1,0,2},{3,1,2,0},{3,2,0,1},{3,2,1,0}
};

// one wave per (b,f): lanes split r, shuffle-reduce
__global__ __launch_bounds__(64) void hmean_kernel(const float* __restrict__ features,
                                                   float* __restrict__ out) {
  int bf = blockIdx.x;
  int b = bf / FDIM, f = bf - b * FDIM;
  int lane = threadIdx.x;
  const float* fb = features + (size_t)b * NN * FDIM + f;
  float acc = 0.f;
  for (int r = lane; r < NN; r += 64) {
    int w = 0;
#pragma unroll
    for (int a = 0; a < KK; ++a) {
      int i0 = r - a * DD;
      if (0 <= i0 && i0 < NH) w++;
    }
    acc += (float)w * fb[(size_t)r * FDIM];
  }
#pragma unroll
  for (int off = 32; off > 0; off >>= 1) acc += __shfl_down(acc, off, 64);
  if (lane == 0) out[bf] = acc * (2.0f / (float)NH);
}

// grid: (NCH2, B*CIN*OG). Each thread: s0 = blk*512+t, s1 = s0+256 packed as
// float2; COUT/OG o's via pair-DP perm loop. Per-wave (m,l) softmax partials
// (shuffles only, no extra barriers).
__global__ __launch_bounds__(256, 4) void sims_kernel(
    const float* __restrict__ graph, const float* __restrict__ types,
    const float* __restrict__ ksA, const float* __restrict__ krA,
    const float* __restrict__ kcA, float* __restrict__ simsOut,
    float* __restrict__ partial)
{
  __shared__ float ls[COUT * CIN * 16];
  __shared__ float lr[COUT * CIN * 4];
  __shared__ float lc[COUT * CIN * 4];
  __shared__ float lK2[COUT * CIN];
  int t = threadIdx.x;
  for (int i = t; i < COUT * CIN * 16; i += 256) ls[i] = ksA[i];
  for (int i = t; i < COUT * CIN * 4; i += 256) { lr[i] = krA[i]; lc[i] = kcA[i]; }
  __syncthreads();
  if (t < COUT * CIN) {
    float k2 = 0.f;
#pragma unroll
    for (int u = 0; u < 16; ++u) k2 += ls[t * 16 + u] * ls[t * 16 + u];
#pragma unroll
    for (int u = 0; u < 4; ++u) k2 += lr[t * 4 + u] * lr[t * 4 + u] + lc[t * 4 + u] * lc[t * 4 + u];
    lK2[t] = k2;
  }
  __syncthreads();

  int s0r = blockIdx.x * 512 + t;
  int s1r = s0r + 256;
  bool v0 = (s0r < NSUB), v1 = (s1r < NSUB);
  int s0 = v0 ? s0r : (NSUB - 1);
  int s1 = v1 ? s1r : (NSUB - 1);
  int yi  = blockIdx.y;
  int og  = yi >> 3;
  int bci = yi & 7;
  int b   = bci >> 2;
  int ci  = bci & 3;
  int ii0 = s0 / NH, jj0 = s0 - ii0 * NH;
  int ii1 = s1 / NH, jj1 = s1 - ii1 * NH;

  const float* gi = graph + ((size_t)b * CIN + ci) * NN * NN;
  const float* ti = types + ((size_t)b * CIN + ci) * NN;

  v2f subv[16], rtv[4], ctv[4];
  v2f G2 = 0.f, T2r = 0.f, T2c = 0.f;
#pragma unroll
  for (int a = 0; a < KK; ++a) {
    const float* r0 = gi + (size_t)(ii0 + a * DD) * NN + jj0;
    const float* r1 = gi + (size_t)(ii1 + a * DD) * NN + jj1;
#pragma unroll
    for (int bb = 0; bb < KK; ++bb) {
      v2f v; v.x = r0[bb * DD]; v.y = r1[bb * DD];
      subv[a * 4 + bb] = v;
      G2 += v * v;
    }
    v2f rv; rv.x = ti[ii0 + a * DD]; rv.y = ti[ii1 + a * DD];
    v2f cv; cv.x = ti[jj0 + a * DD]; cv.y = ti[jj1 + a * DD];
    rtv[a] = rv; ctv[a] = cv;
    T2r += rv * rv; T2c += cv * cv;
  }
  v2f base0 = G2 + T2r + T2c;

  int wave = t >> 6, lane = t & 63;

#pragma unroll 1
  for (int oo = 0; oo < COUT / OG; ++oo) {
    int o = og * (COUT / OG) + oo;
    int oc = o * CIN + ci;
    float kS[16], kR[4], kC[4];
    {
      const float4* pS4 = (const float4*)(ls + oc * 16);
#pragma unroll
      for (int u = 0; u < 4; ++u) {
        float4 q = pS4[u];
        kS[u*4+0] = q.x; kS[u*4+1] = q.y; kS[u*4+2] = q.z; kS[u*4+3] = q.w;
      }
      float4 qr = *(const float4*)(lr + oc * 4);
      kR[0] = qr.x; kR[1] = qr.y; kR[2] = qr.z; kR[3] = qr.w;
      float4 qc = *(const float4*)(lc + oc * 4);
      kC[0] = qc.x; kC[1] = qc.y; kC[2] = qc.z; kC[3] = qc.w;
    }

    // C1[a][a'] = diag + row + col contribution for mapping a->a'
    v2f C1[16];
#pragma unroll
    for (int a = 0; a < 4; ++a)
#pragma unroll
      for (int ap = 0; ap < 4; ++ap)
        C1[a * 4 + ap] = subv[a * 4 + a] * kS[ap * 4 + ap]
                       + rtv[a] * kR[ap] + ctv[a] * kC[ap];

    // pair-DP: pair01[x][y] covers positions {0,1} -> (x,y); pair23 likewise.
    v2f pair01[16], pair23[16];
#pragma unroll
    for (int x = 0; x < 4; ++x)
#pragma unroll
      for (int y = 0; y < 4; ++y) {
        if (x == y) continue;
        pair01[x * 4 + y] = C1[0 * 4 + x] + C1[1 * 4 + y]
                          + subv[0*4+1] * kS[x*4+y] + subv[1*4+0] * kS[y*4+x];
        pair23[x * 4 + y] = C1[2 * 4 + x] + C1[3 * 4 + y]
                          + subv[2*4+3] * kS[x*4+y] + subv[3*4+2] * kS[y*4+x];
      }

    v2f maxcr = NEGBIG;
#pragma unroll
    for (int p = 0; p < NPERM; ++p) {
      const int p0 = PERM[p][0], p1 = PERM[p][1], p2 = PERM[p][2], p3 = PERM[p][3];
      v2f cr = pair01[p0 * 4 + p1] + pair23[p2 * 4 + p3];
      cr += subv[0*4+2] * kS[p0*4+p2];
      cr += subv[2*4+0] * kS[p2*4+p0];
      cr += subv[0*4+3] * kS[p0*4+p3];
      cr += subv[3*4+0] * kS[p3*4+p0];
      cr += subv[1*4+2] * kS[p1*4+p2];
      cr += subv[2*4+1] * kS[p2*4+p1];
      cr += subv[1*4+3] * kS[p1*4+p3];
      cr += subv[3*4+1] * kS[p3*4+p1];
      maxcr = __builtin_elementwise_max(maxcr, cr);
    }
    v2f best = base0 + lK2[oc] - 2.0f * maxcr;

    int rowIdx = (b * COUT + o) * CIN + ci;
    size_t rowbase = (size_t)rowIdx * NSUB;
    if (v0) simsOut[rowbase + s0r] = best.x;
    if (v1) simsOut[rowbase + s1r] = best.y;

    // per-wave softmax partial (m, l): shuffles only, no syncthreads
    float bm0 = v0 ? best.x : NEGBIG;
    float bm1 = v1 ? best.y : NEGBIG;
    float m = fmaxf(bm0, bm1);
#pragma unroll
    for (int off = 32; off > 0; off >>= 1) m = fmaxf(m, __shfl_down(m, off, 64));
    m = __shfl(m, 0, 64);
    float e = 0.f;
    if (v0) e += __expf(bm0 - m);
    if (v1) e += __expf(bm1 - m);
#pragma unroll
    for (int off = 32; off > 0; off >>= 1) e += __shfl_down(e, off, 64);
    if (lane == 0) {
      int idx = (rowIdx * NPART + blockIdx.x * NW + wave) * 2;
      partial[idx] = m; partial[idx + 1] = e;
    }
  }
}

// grid (MB, NROWS): fused combine (NPART partials per row, L2-broadcast) +
// in-place transform of this block's chunk.
__global__ __launch_bounds__(256) void softmax_final(float* __restrict__ sims,
                                                     const float* __restrict__ partial) {
  int ch = blockIdx.x, row = blockIdx.y;
  int t = threadIdx.x;

  const float* pp = partial + (size_t)row * NPART * 2;
  float m = NEGBIG, l = 0.f;
  for (int i = t; i < NPART; i += 256) {
    float mi = pp[2 * i], li = pp[2 * i + 1];
    float M = fmaxf(m, mi);
    l = l * __expf(m - M) + li * __expf(mi - M);
    m = M;
  }
  __shared__ float ms[256], lsv[256];
  ms[t] = m; lsv[t] = l;
  __syncthreads();
  for (int off = 128; off > 0; off >>= 1) {
    if (t < off) {
      float m2 = ms[t + off], l2 = lsv[t + off];
      float M = fmaxf(ms[t], m2);
      lsv[t] = lsv[t] * __expf(ms[t] - M) + l2 * __expf(m2 - M);
      ms[t] = M;
    }
    __syncthreads();
  }
  float M = ms[0], invS = 1.0f / lsv[0];

  int base4 = ch * CH4;
  int n4 = NSUB4 - base4; if (n4 > CH4) n4 = CH4;
  float4* rp = (float4*)(sims + (size_t)row * NSUB) + base4;
  const float scale = 1.0f / (float)NSUB;
  for (int i = t; i < n4; i += 256) {
    float4 v = rp[i];
    v.x = (1.0f - __expf(v.x - M) * invS) * scale;
    v.y = (1.0f - __expf(v.y - M) * invS) * scale;
    v.z = (1.0f - __expf(v.z - M) * invS) * scale;
    v.w = (1.0f - __expf(v.w - M) * invS) * scale;
    rp[i] = v;
  }
}

extern "C" void kernel_launch(void* const* d_in, const int* in_sizes, int n_in,
                              void* d_out, int out_size, void* d_ws, size_t ws_size,
                              hipStream_t stream) {
  const float* graph    = (const float*)d_in[0];
  const float* types    = (const float*)d_in[1];
  const float* features = (const float*)d_in[2];
  const float* ks       = (const float*)d_in[3];
  const float* kr       = (const float*)d_in[4];
  const float* kc       = (const float*)d_in[5];
  float* out  = (float*)d_out;
  float* sims = out + B_ * FDIM;

  float* partial = (float*)d_ws;   // NROWS*NPART*2 floats (~190 KB)

  hmean_kernel<<<B_ * FDIM, 64, 0, stream>>>(features, out);
  dim3 sgrid(NCH2, B_ * CIN * OG);
  sims_kernel<<<sgrid, 256, 0, stream>>>(graph, types, ks, kr, kc, sims, partial);
  dim3 pgrid(MB, NROWS);
  softmax_final<<<pgrid, 256, 0, stream>>>(sims, partial);
}